// Round 10
// baseline (48.517 us; speedup 1.0000x reference)
//
#include <hip/hip_runtime.h>
#include <math.h>

#define MAX_T 2048
#define SEG_P 4   // segments per pool block (measured optimum: {1:40.6, 2:37.5, 4:35.3, 8:~39} µs)

typedef float f32x4 __attribute__((ext_vector_type(4)));  // native vec for NT stores

// ---------------- Kernel 1: score = sigmoid(feat . W + b) ----------------
// One wave (64 lanes) per (b,t) row. float4 coalesced loads.
__global__ void score_kernel(const float* __restrict__ feat,
                             const float* __restrict__ W,
                             const float* __restrict__ bias,
                             float* __restrict__ score,
                             int nrows, int D) {
  int row = blockIdx.x * 4 + (threadIdx.x >> 6);
  int lane = threadIdx.x & 63;
  if (row >= nrows) return;
  const float4* f4 = (const float4*)(feat + (size_t)row * D);
  const float4* w4 = (const float4*)W;
  float acc = 0.f;
  int n4 = D >> 2;
  for (int idx = lane; idx < n4; idx += 64) {
    float4 a = f4[idx];
    float4 w = w4[idx];
    acc += a.x * w.x + a.y * w.y + a.z * w.z + a.w * w.w;
  }
#pragma unroll
  for (int off = 32; off > 0; off >>= 1) acc += __shfl_xor(acc, off, 64);
  if (lane == 0) {
    float x = acc + bias[0];
    score[row] = 1.f / (1.f + expf(-x));
  }
}

// ---------------- Kernel 2: valley detect -> vi table (1024 thr) --------
// One block per batch element. vi[j] = frame index of valley j.
// Atom j := [vi[j-1], vi[j]) with vi[-1]:=0 (atom 0 empty since vi[0]==0).
// Segment k = atom k U atom k+1 (k<hn-1); segment hn-1 = atom hn-1.
__global__ __launch_bounds__(1024) void seg_kernel(
    const float* __restrict__ score, const int* __restrict__ hlens,
    int* __restrict__ vi_ws, int* __restrict__ hn_ws,
    float* __restrict__ hn_out, int T, int M) {
  int b = blockIdx.x;
  int tid = threadIdx.x;
  const int NT = 1024;
  __shared__ float s[MAX_T];
  __shared__ unsigned char fl[MAX_T];
  __shared__ int vi[MAX_T];
  __shared__ int wsum[16];

  const float* sr = score + (size_t)b * T;
  int hl = hlens[b];

  for (int t = tid; t < T; t += NT) s[t] = sr[t];
  __syncthreads();

  for (int t = tid; t < T; t += NT) {
    bool f;
    if (t >= hl)                     f = false;
    else if (t == 0 || t == hl - 1)  f = true;
    else {
      float c = s[t];
      f = (c >= s[t - 1]) && (c >= s[t + 1]);
    }
    fl[t] = f ? (unsigned char)1 : (unsigned char)0;
  }
  __syncthreads();

  int C = (T + NT - 1) / NT;            // 2
  int lo = tid * C;
  int hi = lo + C; if (hi > T) hi = T; if (lo > T) lo = T;
  int cnt = 0;
  for (int t = lo; t < hi; ++t) cnt += fl[t];

  int lane = tid & 63, wid = tid >> 6;  // 16 waves
  int incl = cnt;
#pragma unroll
  for (int off = 1; off < 64; off <<= 1) {
    int v = __shfl_up(incl, off, 64);
    if (lane >= off) incl += v;
  }
  if (lane == 63) wsum[wid] = incl;
  __syncthreads();
  int wofs = 0, hn = 0;
#pragma unroll
  for (int w = 0; w < 16; ++w) {
    if (w < wid) wofs += wsum[w];
    hn += wsum[w];
  }
  int excl = wofs + incl - cnt;
  for (int t = lo; t < hi; ++t) {
    if (fl[t]) vi[excl++] = t;
  }
  __syncthreads();

  for (int j = tid; j < M; j += NT) {
    vi_ws[(size_t)b * M + j] = (j < hn) ? vi[j] : 0;
  }
  if (tid == 0) {
    hn_ws[b] = hn;
    hn_out[b] = (float)hn;
  }
}

// ---------------- Kernel 3: single-span rolling-atom pool ----------------
// One 128-thread block per SEG_P consecutive segments. The block walks its
// whole frame span in ONE loop (1-deep prefetch), rolling atom accumulators
// at wave-uniform valley-boundary crossings. Emits segment k = atom k +
// atom k+1 (k<hn-1) and segment hn-1 = atom hn-1 alone.
__global__ __launch_bounds__(128) void pool_kernel(
    const float* __restrict__ feat, const float* __restrict__ score,
    const int* __restrict__ vi_ws, const int* __restrict__ hn_ws,
    float* __restrict__ out, int T, int D, int M, int ngrp) {
  int gid = blockIdx.x;
  int lane = threadIdx.x;                 // 128 lanes x float4 = D=512
  int b = gid / ngrp;
  int g = gid - b * ngrp;
  int k0 = g * SEG_P;
  if (k0 >= M) return;
  int kend = k0 + SEG_P; if (kend > M) kend = M;

  int hn = hn_ws[b];
  int klast = kend < hn ? kend : hn;      // segments [k0, klast) are valid

  // zero-fill invalid segments up front
  for (int k = klast; k < kend; ++k) {
    f32x4 z = (f32x4)(0.f);
    __builtin_nontemporal_store(z, (f32x4*)(out + ((size_t)b * M + k) * D) + lane);
  }
  if (k0 >= hn) return;

  const int* vi = vi_ws + (size_t)b * M;
  const float* sr = score + (size_t)b * T;
  const float4* fr = (const float4*)(feat + (size_t)b * T * (size_t)D);

  int a_lo = k0;
  int a_hi = klast < (hn - 1) ? klast : (hn - 1);   // last atom needed
  int span_s = (a_lo == 0) ? 0 : vi[a_lo - 1];
  int span_e = vi[a_hi];

  float4 ap = make_float4(0.f, 0.f, 0.f, 0.f);      // previous atom
  float ssp = 0.f;
  float4 cur = make_float4(0.f, 0.f, 0.f, 0.f);     // current atom
  float scur = 0.f;

  auto emit = [&](int k, float nx, float ny, float nz, float nw, float den) {
    float inv = 1.f / (den + 1e-10f);
    f32x4 r;
    r.x = nx * inv; r.y = ny * inv; r.z = nz * inv; r.w = nw * inv;
    __builtin_nontemporal_store(r, (f32x4*)(out + ((size_t)b * M + k) * D) + lane);
  };
  auto complete = [&](int j) {            // atom j finished in cur/scur
    if (j > a_lo) {
      int k = j - 1;
      if (k < klast && k < hn - 1)
        emit(k, ap.x + cur.x, ap.y + cur.y, ap.z + cur.z, ap.w + cur.w,
             ssp + scur);
    }
    if (j == hn - 1 && j >= k0 && j < klast)
      emit(j, cur.x, cur.y, cur.z, cur.w, scur);
    ap = cur; ssp = scur;
  };

  int j = a_lo;
  int nextb = vi[j];                      // end frame of atom j
  float4 fnext = (span_s < span_e) ? fr[(size_t)span_s * 128 + lane]
                                   : make_float4(0.f, 0.f, 0.f, 0.f);
  for (int t = span_s; t < span_e; ++t) {
    while (t == nextb) {                  // atom j complete (wave-uniform)
      complete(j);
      ++j; nextb = vi[j];
      cur = make_float4(0.f, 0.f, 0.f, 0.f); scur = 0.f;
    }
    float4 f = fnext;
    if (t + 1 < span_e) fnext = fr[(size_t)(t + 1) * 128 + lane];
    float sc = sr[t];
    cur.x += sc * f.x; cur.y += sc * f.y; cur.z += sc * f.z; cur.w += sc * f.w;
    scur += sc;
  }
  complete(a_hi);                         // span_e == vi[a_hi]
}

extern "C" void kernel_launch(void* const* d_in, const int* in_sizes, int n_in,
                              void* d_out, int out_size, void* d_ws, size_t ws_size,
                              hipStream_t stream) {
  const float* feat = (const float*)d_in[0];
  const float* W    = (const float*)d_in[1];
  const float* bias = (const float*)d_in[2];
  const int* hlens  = (const int*)d_in[3];

  int D = in_sizes[1];                 // 512
  int B = in_sizes[3];                 // 16
  int T = in_sizes[0] / (B * D);       // 2000
  int M = (out_size - B - B * T) / (B * D);  // data-dependent max segments

  float* out      = (float*)d_out;
  float* hn_out   = out + (size_t)B * M * D;      // [B] (as float)
  float* score    = hn_out + B;                   // [B, T]

  // ws layout: vi[B*M] int | hn_ws[B] int
  int* vi_ws = (int*)d_ws;
  int* hn_ws = vi_ws + (size_t)B * M;

  int nrows = B * T;
  score_kernel<<<(nrows + 3) / 4, 256, 0, stream>>>(feat, W, bias, score, nrows, D);
  seg_kernel<<<B, 1024, 0, stream>>>(score, hlens, vi_ws, hn_ws, hn_out, T, M);

  int ngrp = (M + SEG_P - 1) / SEG_P;
  pool_kernel<<<B * ngrp, 128, 0, stream>>>(feat, score, vi_ws, hn_ws,
                                            out, T, D, M, ngrp);
}